// Round 6
// baseline (1224.608 us; speedup 1.0000x reference)
//
#include <hip/hip_runtime.h>

typedef unsigned int uint32;
typedef unsigned short u16;
typedef __attribute__((ext_vector_type(4))) float f32x4;
typedef __attribute__((ext_vector_type(8))) short bf16x8;

#define HID 1024
#define NTOK 32768  // B*S = 4*8192

// ---------- bf16 helpers (RNE, raw bits; inputs are finite) ----------
__device__ __forceinline__ u16 f2bf(float f) {
    uint32 u = __builtin_bit_cast(uint32, f);
    u += 0x7FFFu + ((u >> 16) & 1u);
    return (u16)(u >> 16);
}
__device__ __forceinline__ float bf2f(u16 h) {
    uint32 u = ((uint32)h) << 16;
    return __builtin_bit_cast(float, u);
}

// async global->LDS, 16B per lane, LDS dest = wave-uniform base + lane*16
__device__ __forceinline__ void async16(const void* g, void* l) {
    __builtin_amdgcn_global_load_lds(
        (const __attribute__((address_space(1))) uint32*)g,
        (__attribute__((address_space(3))) uint32*)l, 16, 0, 0);
}

// ---------- fp32 -> (hi,lo) bf16 split, 4 elems/thread ----------
__global__ __launch_bounds__(256) void split_kernel(const float* __restrict__ x,
                                                    u16* __restrict__ hi,
                                                    u16* __restrict__ lo,
                                                    int n) {
    int i = (blockIdx.x * 256 + threadIdx.x) * 4;
    if (i >= n) return;
    float4 v = *reinterpret_cast<const float4*>(x + i);
    u16 h0 = f2bf(v.x), h1 = f2bf(v.y), h2 = f2bf(v.z), h3 = f2bf(v.w);
    u16 l0 = f2bf(v.x - bf2f(h0)), l1 = f2bf(v.y - bf2f(h1));
    u16 l2 = f2bf(v.z - bf2f(h2)), l3 = f2bf(v.w - bf2f(h3));
    *reinterpret_cast<uint2*>(hi + i) =
        make_uint2((uint32)h0 | ((uint32)h1 << 16), (uint32)h2 | ((uint32)h3 << 16));
    *reinterpret_cast<uint2*>(lo + i) =
        make_uint2((uint32)l0 | ((uint32)l1 << 16), (uint32)l2 | ((uint32)l3 << 16));
}

// ---------- split-bf16 GEMM: C[m,n] = sum_k A[m,k]*W[n,k] (fp32 out) ----------
// 128x128 tile, BK=32, 4 waves, each wave 64x64 (4x4 frags of 16x16x32 MFMA).
// T2 both-sides XOR swizzle (verified r4: SQ_LDS_BANK_CONFLICT == 0, bit-exact).
// T4 counted vmcnt (r6): raw s_barrier pairs + s_waitcnt vmcnt(8) — next tile's
// 8 global_load_lds stay in flight across both barriers; no vmcnt(0) drain in
// the main loop (m218 lever). Empty asm memory fences pin loads to their phase
// (s_barrier is IntrNoMem in LLVM, so it alone doesn't fence).
__device__ __forceinline__ void gemm_body(const u16* __restrict__ Ahi,
                                          const u16* __restrict__ Alo,
                                          const u16* __restrict__ Bhi,
                                          const u16* __restrict__ Blo,
                                          float* __restrict__ C) {
    __shared__ u16 sAh[2][128 * 32], sAl[2][128 * 32];
    __shared__ u16 sBh[2][128 * 32], sBl[2][128 * 32];
    const int tid = threadIdx.x;
    const int wave = tid >> 6, lane = tid & 63;
    const int m0 = blockIdx.x * 128, n0 = blockIdx.y * 128;
    const int wm = (wave >> 1) * 64, wn = (wave & 1) * 64;
    const int srow = lane >> 2;                               // staging row in segment
    const int scol = ((lane & 3) ^ ((lane >> 3) & 3)) * 8;    // swizzled source k-slot
    const int fr = lane & 15;                                 // fragment row/col
    const int ks = (((lane >> 4) ^ ((lane >> 1) & 3)) & 3) * 8;  // swizzled LDS k-slot

    const int seg0 = wave * 2, seg1 = wave * 2 + 1;
    const int r0g = seg0 * 16 + srow, r1g = seg1 * 16 + srow;

    f32x4 acc[4][4];
#pragma unroll
    for (int a = 0; a < 4; a++)
#pragma unroll
        for (int b = 0; b < 4; b++) acc[a][b] = f32x4{0.f, 0.f, 0.f, 0.f};

    // stage one K-tile (8 loads/wave) into buffer `buf`
    auto stage = [&](int buf, int kk) {
        const size_t ga0 = (size_t)(m0 + r0g) * HID + kk + scol;
        const size_t ga1 = (size_t)(m0 + r1g) * HID + kk + scol;
        const size_t gb0 = (size_t)(n0 + r0g) * HID + kk + scol;
        const size_t gb1 = (size_t)(n0 + r1g) * HID + kk + scol;
        async16(Ahi + ga0, &sAh[buf][seg0 * 512]);
        async16(Ahi + ga1, &sAh[buf][seg1 * 512]);
        async16(Alo + ga0, &sAl[buf][seg0 * 512]);
        async16(Alo + ga1, &sAl[buf][seg1 * 512]);
        async16(Bhi + gb0, &sBh[buf][seg0 * 512]);
        async16(Bhi + gb1, &sBh[buf][seg1 * 512]);
        async16(Blo + gb0, &sBl[buf][seg0 * 512]);
        async16(Blo + gb1, &sBl[buf][seg1 * 512]);
    };

    stage(0, 0);  // prologue

    int cur = 0;
    for (int k0 = 0; k0 < HID; k0 += 32) {
        const bool last = (k0 + 32 >= HID);
        if (!last) {
            stage(cur ^ 1, k0 + 32);
            // wait only tile-t's 8 loads (oldest); tile-(t+1)'s 8 stay in flight
            asm volatile("s_waitcnt vmcnt(8)" ::: "memory");
        } else {
            asm volatile("s_waitcnt vmcnt(0)" ::: "memory");
        }
        __builtin_amdgcn_s_barrier();          // all waves' tile-t stores visible
        asm volatile("" ::: "memory");

        bf16x8 fah[4], fal[4], fbh[4], fbl[4];
#pragma unroll
        for (int a = 0; a < 4; a++) {
            const int row = wm + a * 16 + fr;
            fah[a] = *reinterpret_cast<const bf16x8*>(&sAh[cur][row * 32 + ks]);
            fal[a] = *reinterpret_cast<const bf16x8*>(&sAl[cur][row * 32 + ks]);
        }
#pragma unroll
        for (int b = 0; b < 4; b++) {
            const int row = wn + b * 16 + fr;
            fbh[b] = *reinterpret_cast<const bf16x8*>(&sBh[cur][row * 32 + ks]);
            fbl[b] = *reinterpret_cast<const bf16x8*>(&sBl[cur][row * 32 + ks]);
        }

        __builtin_amdgcn_s_setprio(1);
        // product 1: Ahi*Bhi
#pragma unroll
        for (int a = 0; a < 4; a++)
#pragma unroll
            for (int b = 0; b < 4; b++)
                acc[a][b] = __builtin_amdgcn_mfma_f32_16x16x32_bf16(fah[a], fbh[b], acc[a][b], 0, 0, 0);
        // product 2: Ahi*Blo
#pragma unroll
        for (int a = 0; a < 4; a++)
#pragma unroll
            for (int b = 0; b < 4; b++)
                acc[a][b] = __builtin_amdgcn_mfma_f32_16x16x32_bf16(fah[a], fbl[b], acc[a][b], 0, 0, 0);
        // product 3: Alo*Bhi
#pragma unroll
        for (int a = 0; a < 4; a++)
#pragma unroll
            for (int b = 0; b < 4; b++)
                acc[a][b] = __builtin_amdgcn_mfma_f32_16x16x32_bf16(fal[a], fbh[b], acc[a][b], 0, 0, 0);
        __builtin_amdgcn_s_setprio(0);

        asm volatile("" ::: "memory");
        __builtin_amdgcn_s_barrier();          // all waves done reading buf[cur]
        asm volatile("" ::: "memory");
        cur ^= 1;
    }

    // epilogue: D col = lane&15, row = (lane>>4)*4 + j  [verified m89/m91]
    const int col = lane & 15, rr = (lane >> 4) * 4;
#pragma unroll
    for (int a = 0; a < 4; a++)
#pragma unroll
        for (int b = 0; b < 4; b++)
#pragma unroll
            for (int j = 0; j < 4; j++)
                C[(size_t)(m0 + wm + a * 16 + rr + j) * HID + (n0 + wn + b * 16 + col)] =
                    acc[a][b][j];
}

__global__ __launch_bounds__(256) void gemm_qkv(
    const u16* __restrict__ xhi, const u16* __restrict__ xlo,
    const u16* __restrict__ w0h, const u16* __restrict__ w0l,
    const u16* __restrict__ w1h, const u16* __restrict__ w1l,
    const u16* __restrict__ w2h, const u16* __restrict__ w2l,
    float* __restrict__ q, float* __restrict__ k, float* __restrict__ v) {
    const u16 *bh, *bl;
    float* c;
    if (blockIdx.z == 0)      { bh = w0h; bl = w0l; c = q; }
    else if (blockIdx.z == 1) { bh = w1h; bl = w1l; c = k; }
    else                      { bh = w2h; bl = w2l; c = v; }
    gemm_body(xhi, xlo, bh, bl, c);
}

__global__ __launch_bounds__(256) void gemm_one(
    const u16* __restrict__ ahi, const u16* __restrict__ alo,
    const u16* __restrict__ bh, const u16* __restrict__ bl,
    float* __restrict__ c) {
    gemm_body(ahi, alo, bh, bl, c);
}

// ---------- per-token 32x32 attention (fp32), masks fused, writes attn hi/lo bf16 ----------
// 4 waves/block, 1 token/wave. Lane = 2*h + half; half covers 16 t (scores) / 16 d (PV).
__global__ __launch_bounds__(256) void attn_kernel(
    const float* __restrict__ Q, const float* __restrict__ K, const float* __restrict__ V,
    const float* __restrict__ mu_q, const float* __restrict__ sigma_q,
    const float* __restrict__ mu_kv, const float* __restrict__ sigma_kv,
    const float* __restrict__ eps_q, const float* __restrict__ eps_kv,
    u16* __restrict__ Ohi, u16* __restrict__ Olo) {
    // mat 0: q (reused as softmax weights after q consumed), 1: k, 2: v
    __shared__ float sm[4][3][32 * 33];
    __shared__ float mq[32], mkv[32];
    const int tid = threadIdx.x, wave = tid >> 6, lane = tid & 63;

    if (tid < 32) {
        mq[tid] = 1.f / (1.f + __expf(-(mu_q[tid] + eps_q[tid] * sigma_q[tid])));
    } else if (tid < 64) {
        const int d = tid - 32;
        mkv[d] = 1.f / (1.f + __expf(-(mu_kv[d] + eps_kv[d] * sigma_kv[d])));
    }
    __syncthreads();

    const size_t T = (size_t)blockIdx.x * 4 + wave;
    const float* src0 = Q + T * HID;
    const float* src1 = K + T * HID;
    const float* src2 = V + T * HID;
#pragma unroll
    for (int m = 0; m < 3; m++) {
        const float* s = (m == 0) ? src0 : (m == 1) ? src1 : src2;
        const float* msk = (m == 0) ? mq : mkv;
#pragma unroll
        for (int i = 0; i < 4; i++) {
            const int e = (i * 64 + lane) * 4;
            float4 v4 = *reinterpret_cast<const float4*>(s + e);
            const int r = e >> 5, c = e & 31;
            float* dst = &sm[wave][m][r * 33 + c];
            dst[0] = v4.x * msk[c];
            dst[1] = v4.y * msk[c + 1];
            dst[2] = v4.z * msk[c + 2];
            dst[3] = v4.w * msk[c + 3];
        }
    }
    __syncthreads();

    const int h = lane >> 1, half = lane & 1;
    // q row into registers (then sm[wave][0] is reusable for weights)
    float qreg[32];
    const float* qr = &sm[wave][0][h * 33];
#pragma unroll
    for (int d = 0; d < 32; d++) qreg[d] = qr[d];

    // scores for 16 t's
    float sc[16];
    const float* kr = &sm[wave][1][0];
#pragma unroll
    for (int t1 = 0; t1 < 16; t1++) {
        const int t = half * 16 + t1;
        float a = 0.f;
#pragma unroll
        for (int d = 0; d < 32; d++) a += qreg[d] * kr[t * 33 + d];
        sc[t1] = a * 0.17677669529663687f;  // 1/sqrt(32)
    }
    // softmax over 32 t (2 lanes per row)
    float mx = sc[0];
#pragma unroll
    for (int t1 = 1; t1 < 16; t1++) mx = fmaxf(mx, sc[t1]);
    mx = fmaxf(mx, __shfl_xor(mx, 1));
    float sum = 0.f;
#pragma unroll
    for (int t1 = 0; t1 < 16; t1++) {
        sc[t1] = __expf(sc[t1] - mx);
        sum += sc[t1];
    }
    sum += __shfl_xor(sum, 1);
    const float inv = 1.f / sum;
    float* wrow = &sm[wave][0][h * 33];
#pragma unroll
    for (int t1 = 0; t1 < 16; t1++) wrow[half * 16 + t1] = sc[t1] * inv;
    __syncthreads();

    // PV: attn[h][d] = sum_t w[h][t] * v[t][d], this lane: d in [half*16, half*16+16)
    float acc[16];
#pragma unroll
    for (int j = 0; j < 16; j++) acc[j] = 0.f;
    const float* vr = &sm[wave][2][0];
#pragma unroll 4
    for (int t = 0; t < 32; t++) {
        const float wv = wrow[t];
#pragma unroll
        for (int j = 0; j < 16; j++) acc[j] += wv * vr[t * 33 + half * 16 + j];
    }

    // write attn as hi/lo bf16
    u16 hs[16], ls[16];
#pragma unroll
    for (int j = 0; j < 16; j++) {
        hs[j] = f2bf(acc[j]);
        ls[j] = f2bf(acc[j] - bf2f(hs[j]));
    }
    const size_t base = T * HID + h * 32 + half * 16;
    uint32 ph[8], pl[8];
#pragma unroll
    for (int j = 0; j < 8; j++) {
        ph[j] = (uint32)hs[2 * j] | ((uint32)hs[2 * j + 1] << 16);
        pl[j] = (uint32)ls[2 * j] | ((uint32)ls[2 * j + 1] << 16);
    }
    *reinterpret_cast<uint4*>(Ohi + base)     = make_uint4(ph[0], ph[1], ph[2], ph[3]);
    *reinterpret_cast<uint4*>(Ohi + base + 8) = make_uint4(ph[4], ph[5], ph[6], ph[7]);
    *reinterpret_cast<uint4*>(Olo + base)     = make_uint4(pl[0], pl[1], pl[2], pl[3]);
    *reinterpret_cast<uint4*>(Olo + base + 8) = make_uint4(pl[4], pl[5], pl[6], pl[7]);
}

// ---------- KL scalar ----------
__global__ void kl_kernel(const float* __restrict__ mu_q, const float* __restrict__ sigma_q,
                          const float* __restrict__ mu_kv, const float* __restrict__ sigma_kv,
                          float* __restrict__ out) {
    const int l = threadIdx.x;
    float t;
    if (l < 32) {
        t = 1.f + sigma_q[l] - mu_q[l] * mu_q[l] - expf(sigma_q[l]);
    } else {
        const int d = l - 32;
        t = 1.f + sigma_kv[d] - mu_kv[d] * mu_kv[d] - expf(sigma_kv[d]);
    }
    t *= -0.5f / 32.f;
#pragma unroll
    for (int o = 32; o > 0; o >>= 1) t += __shfl_down(t, o);
    if (l == 0) out[0] = t;
}

extern "C" void kernel_launch(void* const* d_in, const int* in_sizes, int n_in,
                              void* d_out, int out_size, void* d_ws, size_t ws_size,
                              hipStream_t stream) {
    const float* hidden   = (const float*)d_in[0];
    const float* wq       = (const float*)d_in[1];
    const float* wk       = (const float*)d_in[2];
    const float* wv       = (const float*)d_in[3];
    const float* wo       = (const float*)d_in[4];
    const float* mu_q     = (const float*)d_in[5];
    const float* sigma_q  = (const float*)d_in[6];
    const float* mu_kv    = (const float*)d_in[7];
    const float* sigma_kv = (const float*)d_in[8];
    const float* eps_q    = (const float*)d_in[9];
    const float* eps_kv   = (const float*)d_in[10];
    float* out = (float*)d_out;

    // ---- workspace-adaptive chunking ----
    // static: 8 weight-split buffers (16 MB). per token (chunk-resident):
    //   xh+xl (bf16, reused as attn hi/lo out): 4 KB; q,k,v fp32: 12 KB -> 16 KB.
    const size_t WN = (size_t)HID * HID;         // elems per weight buffer
    const size_t WBYTES = 8 * WN * 2;            // 16 MB
    int CH = NTOK;                               // tokens per chunk (power of two)
    while (CH > 128 && WBYTES + (size_t)CH * 16384 > ws_size) CH >>= 1;

    char* ws = (char*)d_ws;
    u16* wsp = (u16*)ws;
    u16 *wqh = wsp + 0 * WN, *wql = wsp + 1 * WN;
    u16 *wkh = wsp + 2 * WN, *wkl = wsp + 3 * WN;
    u16 *wvh = wsp + 4 * WN, *wvl = wsp + 5 * WN;
    u16 *woh = wsp + 6 * WN, *wol = wsp + 7 * WN;
    char* dyn = ws + WBYTES;
    u16*   xh = (u16*)dyn;                       // CH*1024 bf16
    u16*   xl = xh + (size_t)CH * HID;
    float* q  = (float*)(xl + (size_t)CH * HID);
    float* k  = q + (size_t)CH * HID;
    float* v  = k + (size_t)CH * HID;

    // weight splits (once)
    split_kernel<<<1024, 256, 0, stream>>>(wq, wqh, wql, HID * HID);
    split_kernel<<<1024, 256, 0, stream>>>(wk, wkh, wkl, HID * HID);
    split_kernel<<<1024, 256, 0, stream>>>(wv, wvh, wvl, HID * HID);
    split_kernel<<<1024, 256, 0, stream>>>(wo, woh, wol, HID * HID);

    const int nchunks = NTOK / CH;
    for (int c = 0; c < nchunks; ++c) {
        const size_t off = (size_t)c * CH * HID;
        // 1) split hidden chunk -> xh/xl
        split_kernel<<<CH, 256, 0, stream>>>(hidden + off, xh, xl, CH * HID);
        // 2) q,k,v projections for chunk
        dim3 gqkv(CH / 128, HID / 128, 3);
        gemm_qkv<<<gqkv, 256, 0, stream>>>(xh, xl, wqh, wql, wkh, wkl, wvh, wvl, q, k, v);
        // 3) per-token attention -> attn hi/lo (reuses xh/xl buffers)
        attn_kernel<<<CH / 4, 256, 0, stream>>>(q, k, v, mu_q, sigma_q, mu_kv, sigma_kv,
                                                eps_q, eps_kv, xh, xl);
        // 4) output projection -> d_out chunk
        dim3 gout(CH / 128, HID / 128, 1);
        gemm_one<<<gout, 256, 0, stream>>>(xh, xl, woh, wol, out + off);
    }

    // 5) KL scalar -> last element of d_out
    kl_kernel<<<1, 64, 0, stream>>>(mu_q, sigma_q, mu_kv, sigma_kv, out + (out_size - 1));
}

// Round 7
// 1063.690 us; speedup vs baseline: 1.1513x; 1.1513x over previous
//
#include <hip/hip_runtime.h>

typedef unsigned int uint32;
typedef unsigned short u16;
typedef __attribute__((ext_vector_type(4))) float f32x4;
typedef __attribute__((ext_vector_type(8))) short bf16x8;

#define HID 1024
#define NTOK 32768  // B*S = 4*8192
#define MFMA16 __builtin_amdgcn_mfma_f32_16x16x32_bf16

// ---------- bf16 helpers (RNE, raw bits; inputs are finite) ----------
__device__ __forceinline__ u16 f2bf(float f) {
    uint32 u = __builtin_bit_cast(uint32, f);
    u += 0x7FFFu + ((u >> 16) & 1u);
    return (u16)(u >> 16);
}
__device__ __forceinline__ float bf2f(u16 h) {
    uint32 u = ((uint32)h) << 16;
    return __builtin_bit_cast(float, u);
}

// async global->LDS, 16B per lane, LDS dest = wave-uniform base + lane*16
__device__ __forceinline__ void async16(const void* g, void* l) {
    __builtin_amdgcn_global_load_lds(
        (const __attribute__((address_space(1))) uint32*)g,
        (__attribute__((address_space(3))) uint32*)l, 16, 0, 0);
}

// ---------- fp32 -> (hi,lo) bf16 split, 4 elems/thread ----------
__global__ __launch_bounds__(256) void split_kernel(const float* __restrict__ x,
                                                    u16* __restrict__ hi,
                                                    u16* __restrict__ lo,
                                                    int n) {
    int i = (blockIdx.x * 256 + threadIdx.x) * 4;
    if (i >= n) return;
    float4 v = *reinterpret_cast<const float4*>(x + i);
    u16 h0 = f2bf(v.x), h1 = f2bf(v.y), h2 = f2bf(v.z), h3 = f2bf(v.w);
    u16 l0 = f2bf(v.x - bf2f(h0)), l1 = f2bf(v.y - bf2f(h1));
    u16 l2 = f2bf(v.z - bf2f(h2)), l3 = f2bf(v.w - bf2f(h3));
    *reinterpret_cast<uint2*>(hi + i) =
        make_uint2((uint32)h0 | ((uint32)h1 << 16), (uint32)h2 | ((uint32)h3 << 16));
    *reinterpret_cast<uint2*>(lo + i) =
        make_uint2((uint32)l0 | ((uint32)l1 << 16), (uint32)l2 | ((uint32)l3 << 16));
}

// ---------- split-bf16 GEMM, 256x256 8-phase (m201 template port) ----------
// C[m,n] = sum_k A[m,k]*W[n,k], 3 products (AhBh + AhBl + AlBh), fp32 out.
// 512 thr = 8 waves (2M x 4N), per-wave 128x64 = 8x4 frags of 16x16x32 bf16.
// LDS: 4 matrices (Ah,Al,Bh,Bl) x 2 dbuf x 256x32 bf16 = 128 KB, 1 block/CU.
// Per K-tile (BK=32): 4 phases {ds_read subtile | stage (ph0/1, 4 loads) |
// barrier | setprio+24 MFMA+setprio | barrier}; vmcnt(0) once per tile at ph3
// (loads have ~2.5 phases in flight). Swizzle pair from r4 (conflict-free,
// bit-exact). Per-accumulator addition order identical to r4-r6 => bit-exact.
__device__ __forceinline__ void gemm_body(const u16* __restrict__ Ahi,
                                          const u16* __restrict__ Alo,
                                          const u16* __restrict__ Bhi,
                                          const u16* __restrict__ Blo,
                                          float* __restrict__ C) {
    __shared__ u16 smem[2][4 * 8192];  // regions: Ah 0, Al 8192, Bh 16384, Bl 24576
    const int tid = threadIdx.x;
    const int wid = tid >> 6, lane = tid & 63;
    const int m0 = blockIdx.x * 256, n0 = blockIdx.y * 256;
    const int wm = (wid >> 2) * 128, wn = (wid & 3) * 64;
    const int srow = lane >> 2;                               // staging row in segment
    const int scol = ((lane & 3) ^ ((lane >> 3) & 3)) * 8;    // swizzled source k-slot
    const int fr = lane & 15;                                 // fragment row
    const int ks = (((lane >> 4) ^ ((lane >> 1) & 3)) & 3) * 8;  // swizzled LDS k-slot

    // staging map: wave w stages matrix (w>>1), segments (w&1)*8 .. +7
    const int mat = wid >> 1;
    const int sbase = (wid & 1) * 8;
    const u16* gsrc = (mat == 0) ? Ahi : (mat == 1) ? Alo : (mat == 2) ? Bhi : Blo;
    const int rbase = (mat < 2) ? m0 : n0;
    const int lregion = mat * 8192;

    f32x4 acc[8][4];
#pragma unroll
    for (int i = 0; i < 8; i++)
#pragma unroll
        for (int j = 0; j < 4; j++) acc[i][j] = f32x4{0.f, 0.f, 0.f, 0.f};

    // prologue: stage K-tile 0 into buf 0, drain, barrier
#pragma unroll
    for (int j = 0; j < 8; j++)
        async16(gsrc + (size_t)(rbase + (sbase + j) * 16 + srow) * HID + scol,
                &smem[0][lregion + (sbase + j) * 512]);
    asm volatile("s_waitcnt vmcnt(0)" ::: "memory");
    __builtin_amdgcn_s_barrier();
    asm volatile("" ::: "memory");

    for (int k0 = 0; k0 < HID; k0 += 32) {
        const int buf = (k0 >> 5) & 1;
        const int nbuf = buf ^ 1;
        const bool notlast = (k0 + 32) < HID;
        const u16* sb = smem[buf];
        bf16x8 fbh[4], fbl[4];
#pragma unroll
        for (int ph = 0; ph < 4; ph++) {
            // ds_read: B frags once (ph0), A frags 2/phase
            if (ph == 0) {
#pragma unroll
                for (int jn = 0; jn < 4; jn++) {
                    const int row = wn + jn * 16 + fr;
                    fbh[jn] = *reinterpret_cast<const bf16x8*>(&sb[16384 + row * 32 + ks]);
                    fbl[jn] = *reinterpret_cast<const bf16x8*>(&sb[24576 + row * 32 + ks]);
                }
            }
            bf16x8 fah[2], fal[2];
#pragma unroll
            for (int ii = 0; ii < 2; ii++) {
                const int row = wm + (ph * 2 + ii) * 16 + fr;
                fah[ii] = *reinterpret_cast<const bf16x8*>(&sb[row * 32 + ks]);
                fal[ii] = *reinterpret_cast<const bf16x8*>(&sb[8192 + row * 32 + ks]);
            }
            // stage next tile early (ph0: segs 0-3, ph1: segs 4-7)
            if (notlast && ph < 2) {
#pragma unroll
                for (int jj = 0; jj < 4; jj++) {
                    const int j = ph * 4 + jj;
                    async16(gsrc + (size_t)(rbase + (sbase + j) * 16 + srow) * HID +
                                (k0 + 32) + scol,
                            &smem[nbuf][lregion + (sbase + j) * 512]);
                }
            }
            asm volatile("" ::: "memory");
            __builtin_amdgcn_s_barrier();
            asm volatile("" ::: "memory");

            __builtin_amdgcn_s_setprio(1);
#pragma unroll
            for (int jn = 0; jn < 4; jn++)
#pragma unroll
                for (int ii = 0; ii < 2; ii++)
                    acc[ph * 2 + ii][jn] = MFMA16(fah[ii], fbh[jn], acc[ph * 2 + ii][jn], 0, 0, 0);
#pragma unroll
            for (int jn = 0; jn < 4; jn++)
#pragma unroll
                for (int ii = 0; ii < 2; ii++)
                    acc[ph * 2 + ii][jn] = MFMA16(fah[ii], fbl[jn], acc[ph * 2 + ii][jn], 0, 0, 0);
#pragma unroll
            for (int jn = 0; jn < 4; jn++)
#pragma unroll
                for (int ii = 0; ii < 2; ii++)
                    acc[ph * 2 + ii][jn] = MFMA16(fal[ii], fbh[jn], acc[ph * 2 + ii][jn], 0, 0, 0);
            __builtin_amdgcn_s_setprio(0);

            asm volatile("" ::: "memory");
            if (ph == 3 && notlast)
                asm volatile("s_waitcnt vmcnt(0)" ::: "memory");  // next buf complete
            __builtin_amdgcn_s_barrier();
            asm volatile("" ::: "memory");
        }
    }

    // epilogue: D col = lane&15, row = (lane>>4)*4 + j  [verified m89/m91]
    const int col = lane & 15, rr = (lane >> 4) * 4;
#pragma unroll
    for (int i = 0; i < 8; i++)
#pragma unroll
        for (int jn = 0; jn < 4; jn++)
#pragma unroll
            for (int j = 0; j < 4; j++)
                C[(size_t)(m0 + wm + i * 16 + rr + j) * HID + (n0 + wn + jn * 16 + col)] =
                    acc[i][jn][j];
}

__global__ __launch_bounds__(512, 2) void gemm_qkv(
    const u16* __restrict__ xhi, const u16* __restrict__ xlo,
    const u16* __restrict__ w0h, const u16* __restrict__ w0l,
    const u16* __restrict__ w1h, const u16* __restrict__ w1l,
    const u16* __restrict__ w2h, const u16* __restrict__ w2l,
    float* __restrict__ q, float* __restrict__ k, float* __restrict__ v) {
    const u16 *bh, *bl;
    float* c;
    if (blockIdx.z == 0)      { bh = w0h; bl = w0l; c = q; }
    else if (blockIdx.z == 1) { bh = w1h; bl = w1l; c = k; }
    else                      { bh = w2h; bl = w2l; c = v; }
    gemm_body(xhi, xlo, bh, bl, c);
}

__global__ __launch_bounds__(512, 2) void gemm_one(
    const u16* __restrict__ ahi, const u16* __restrict__ alo,
    const u16* __restrict__ bh, const u16* __restrict__ bl,
    float* __restrict__ c) {
    gemm_body(ahi, alo, bh, bl, c);
}

// ---------- per-token 32x32 attention (fp32), masks fused, writes attn hi/lo bf16 ----------
// 4 waves/block, 1 token/wave. Lane = 2*h + half; half covers 16 t (scores) / 16 d (PV).
__global__ __launch_bounds__(256) void attn_kernel(
    const float* __restrict__ Q, const float* __restrict__ K, const float* __restrict__ V,
    const float* __restrict__ mu_q, const float* __restrict__ sigma_q,
    const float* __restrict__ mu_kv, const float* __restrict__ sigma_kv,
    const float* __restrict__ eps_q, const float* __restrict__ eps_kv,
    u16* __restrict__ Ohi, u16* __restrict__ Olo) {
    // mat 0: q (reused as softmax weights after q consumed), 1: k, 2: v
    __shared__ float sm[4][3][32 * 33];
    __shared__ float mq[32], mkv[32];
    const int tid = threadIdx.x, wave = tid >> 6, lane = tid & 63;

    if (tid < 32) {
        mq[tid] = 1.f / (1.f + __expf(-(mu_q[tid] + eps_q[tid] * sigma_q[tid])));
    } else if (tid < 64) {
        const int d = tid - 32;
        mkv[d] = 1.f / (1.f + __expf(-(mu_kv[d] + eps_kv[d] * sigma_kv[d])));
    }
    __syncthreads();

    const size_t T = (size_t)blockIdx.x * 4 + wave;
    const float* src0 = Q + T * HID;
    const float* src1 = K + T * HID;
    const float* src2 = V + T * HID;
#pragma unroll
    for (int m = 0; m < 3; m++) {
        const float* s = (m == 0) ? src0 : (m == 1) ? src1 : src2;
        const float* msk = (m == 0) ? mq : mkv;
#pragma unroll
        for (int i = 0; i < 4; i++) {
            const int e = (i * 64 + lane) * 4;
            float4 v4 = *reinterpret_cast<const float4*>(s + e);
            const int r = e >> 5, c = e & 31;
            float* dst = &sm[wave][m][r * 33 + c];
            dst[0] = v4.x * msk[c];
            dst[1] = v4.y * msk[c + 1];
            dst[2] = v4.z * msk[c + 2];
            dst[3] = v4.w * msk[c + 3];
        }
    }
    __syncthreads();

    const int h = lane >> 1, half = lane & 1;
    // q row into registers (then sm[wave][0] is reusable for weights)
    float qreg[32];
    const float* qr = &sm[wave][0][h * 33];
#pragma unroll
    for (int d = 0; d < 32; d++) qreg[d] = qr[d];

    // scores for 16 t's
    float sc[16];
    const float* kr = &sm[wave][1][0];
#pragma unroll
    for (int t1 = 0; t1 < 16; t1++) {
        const int t = half * 16 + t1;
        float a = 0.f;
#pragma unroll
        for (int d = 0; d < 32; d++) a += qreg[d] * kr[t * 33 + d];
        sc[t1] = a * 0.17677669529663687f;  // 1/sqrt(32)
    }
    // softmax over 32 t (2 lanes per row)
    float mx = sc[0];
#pragma unroll
    for (int t1 = 1; t1 < 16; t1++) mx = fmaxf(mx, sc[t1]);
    mx = fmaxf(mx, __shfl_xor(mx, 1));
    float sum = 0.f;
#pragma unroll
    for (int t1 = 0; t1 < 16; t1++) {
        sc[t1] = __expf(sc[t1] - mx);
        sum += sc[t1];
    }
    sum += __shfl_xor(sum, 1);
    const float inv = 1.f / sum;
    float* wrow = &sm[wave][0][h * 33];
#pragma unroll
    for (int t1 = 0; t1 < 16; t1++) wrow[half * 16 + t1] = sc[t1] * inv;
    __syncthreads();

    // PV: attn[h][d] = sum_t w[h][t] * v[t][d], this lane: d in [half*16, half*16+16)
    float acc[16];
#pragma unroll
    for (int j = 0; j < 16; j++) acc[j] = 0.f;
    const float* vr = &sm[wave][2][0];
#pragma unroll 4
    for (int t = 0; t < 32; t++) {
        const float wv = wrow[t];
#pragma unroll
        for (int j = 0; j < 16; j++) acc[j] += wv * vr[t * 33 + half * 16 + j];
    }

    // write attn as hi/lo bf16
    u16 hs[16], ls[16];
#pragma unroll
    for (int j = 0; j < 16; j++) {
        hs[j] = f2bf(acc[j]);
        ls[j] = f2bf(acc[j] - bf2f(hs[j]));
    }
    const size_t base = T * HID + h * 32 + half * 16;
    uint32 ph[8], pl[8];
#pragma unroll
    for (int j = 0; j < 8; j++) {
        ph[j] = (uint32)hs[2 * j] | ((uint32)hs[2 * j + 1] << 16);
        pl[j] = (uint32)ls[2 * j] | ((uint32)ls[2 * j + 1] << 16);
    }
    *reinterpret_cast<uint4*>(Ohi + base)     = make_uint4(ph[0], ph[1], ph[2], ph[3]);
    *reinterpret_cast<uint4*>(Ohi + base + 8) = make_uint4(ph[4], ph[5], ph[6], ph[7]);
    *reinterpret_cast<uint4*>(Olo + base)     = make_uint4(pl[0], pl[1], pl[2], pl[3]);
    *reinterpret_cast<uint4*>(Olo + base + 8) = make_uint4(pl[4], pl[5], pl[6], pl[7]);
}

// ---------- KL scalar ----------
__global__ void kl_kernel(const float* __restrict__ mu_q, const float* __restrict__ sigma_q,
                          const float* __restrict__ mu_kv, const float* __restrict__ sigma_kv,
                          float* __restrict__ out) {
    const int l = threadIdx.x;
    float t;
    if (l < 32) {
        t = 1.f + sigma_q[l] - mu_q[l] * mu_q[l] - expf(sigma_q[l]);
    } else {
        const int d = l - 32;
        t = 1.f + sigma_kv[d] - mu_kv[d] * mu_kv[d] - expf(sigma_kv[d]);
    }
    t *= -0.5f / 32.f;
#pragma unroll
    for (int o = 32; o > 0; o >>= 1) t += __shfl_down(t, o);
    if (l == 0) out[0] = t;
}

extern "C" void kernel_launch(void* const* d_in, const int* in_sizes, int n_in,
                              void* d_out, int out_size, void* d_ws, size_t ws_size,
                              hipStream_t stream) {
    const float* hidden   = (const float*)d_in[0];
    const float* wq       = (const float*)d_in[1];
    const float* wk       = (const float*)d_in[2];
    const float* wv       = (const float*)d_in[3];
    const float* wo       = (const float*)d_in[4];
    const float* mu_q     = (const float*)d_in[5];
    const float* sigma_q  = (const float*)d_in[6];
    const float* mu_kv    = (const float*)d_in[7];
    const float* sigma_kv = (const float*)d_in[8];
    const float* eps_q    = (const float*)d_in[9];
    const float* eps_kv   = (const float*)d_in[10];
    float* out = (float*)d_out;

    // ---- workspace-adaptive chunking (min CH=256 for the 256-row GEMM tile) ----
    const size_t WN = (size_t)HID * HID;         // elems per weight buffer
    const size_t WBYTES = 8 * WN * 2;            // 16 MB
    int CH = NTOK;                               // tokens per chunk (power of two)
    while (CH > 256 && WBYTES + (size_t)CH * 16384 > ws_size) CH >>= 1;

    char* ws = (char*)d_ws;
    u16* wsp = (u16*)ws;
    u16 *wqh = wsp + 0 * WN, *wql = wsp + 1 * WN;
    u16 *wkh = wsp + 2 * WN, *wkl = wsp + 3 * WN;
    u16 *wvh = wsp + 4 * WN, *wvl = wsp + 5 * WN;
    u16 *woh = wsp + 6 * WN, *wol = wsp + 7 * WN;
    char* dyn = ws + WBYTES;
    u16*   xh = (u16*)dyn;                       // CH*1024 bf16
    u16*   xl = xh + (size_t)CH * HID;
    float* q  = (float*)(xl + (size_t)CH * HID);
    float* k  = q + (size_t)CH * HID;
    float* v  = k + (size_t)CH * HID;

    // weight splits (once)
    split_kernel<<<1024, 256, 0, stream>>>(wq, wqh, wql, HID * HID);
    split_kernel<<<1024, 256, 0, stream>>>(wk, wkh, wkl, HID * HID);
    split_kernel<<<1024, 256, 0, stream>>>(wv, wvh, wvl, HID * HID);
    split_kernel<<<1024, 256, 0, stream>>>(wo, woh, wol, HID * HID);

    const int nchunks = NTOK / CH;
    for (int c = 0; c < nchunks; ++c) {
        const size_t off = (size_t)c * CH * HID;
        // 1) split hidden chunk -> xh/xl
        split_kernel<<<CH, 256, 0, stream>>>(hidden + off, xh, xl, CH * HID);
        // 2) q,k,v projections for chunk
        dim3 gqkv(CH / 256, HID / 256, 3);
        gemm_qkv<<<gqkv, 512, 0, stream>>>(xh, xl, wqh, wql, wkh, wkl, wvh, wvl, q, k, v);
        // 3) per-token attention -> attn hi/lo (reuses xh/xl buffers)
        attn_kernel<<<CH / 4, 256, 0, stream>>>(q, k, v, mu_q, sigma_q, mu_kv, sigma_kv,
                                                eps_q, eps_kv, xh, xl);
        // 4) output projection -> d_out chunk
        dim3 gout(CH / 256, HID / 256, 1);
        gemm_one<<<gout, 512, 0, stream>>>(xh, xl, woh, wol, out + off);
    }

    // 5) KL scalar -> last element of d_out
    kl_kernel<<<1, 64, 0, stream>>>(mu_q, sigma_q, mu_kv, sigma_kv, out + (out_size - 1));
}